// Round 21
// baseline (104.134 us; speedup 1.0000x reference)
//
#include <hip/hip_runtime.h>
#include <hip/hip_fp16.h>
#include <math.h>

typedef unsigned short u16;
typedef short s16x8 __attribute__((ext_vector_type(8)));
typedef _Float16 f16x8 __attribute__((ext_vector_type(8)));
typedef float f32x4 __attribute__((ext_vector_type(4)));
typedef unsigned int u32x2 __attribute__((ext_vector_type(2)));

constexpr int CB = 4, CN = 512, CD = 256, CH = 8, CHD = 32;
constexpr float CEPS = 1e-5f;
constexpr int M_ROWS = CB * CN; // 2048
constexpr float QSCALE = 0.17677669529663687f; // 32^-0.5

// ---- workspace layout (byte offsets) ----
constexpr size_t O_XB    = 0;                      // u16 [2048][256]
constexpr size_t O_QB    = 1048576;                // u16 [2048][256] (pre-scaled)
constexpr size_t O_KB    = 2097152;                // u16 [2048][256]
constexpr size_t O_VT    = 3145728;                // u16 [4][8][32][512] pos-space
constexpr size_t O_WQKVT = 4194304;                // u16 [768][256]
constexpr size_t O_WOUTT = O_WQKVT + 393216;       // u16 [256][256]
constexpr size_t O_WF1T  = O_WOUTT + 131072;       // u16 [1024][256]
constexpr size_t O_WF2T  = O_WF1T + 524288;        // u16 [256][1024]
constexpr size_t O_WP2T  = O_WF2T + 524288;        // fp16 [16][256] (pad h>=8 = 0)
constexpr size_t O_PACKED= O_WP2T + 8192;          // u32 [128 pairs][4] half2 {w0,w1,w2,b}
constexpr size_t O_JIDX  = O_PACKED + 4096;        // int [4][512] compacted j indices
constexpr size_t O_BIAS  = O_JIDX + 8192;          // u16 [4][8][512][512] bf16 (pos-space)
constexpr size_t O_AOUT  = O_BIAS + 16777216;      // u16 [2048][256]
constexpr size_t O_H1B   = O_AOUT + 1048576;       // u16 [2048][1024]
constexpr size_t O_X1B   = O_H1B + 4194304;        // u16 [2048][256] LN1 out (bf16)
constexpr size_t O_XRF   = O_X1B + 1048576;        // f32 [2048][256] LN1 out (f32)
constexpr size_t O_CNT   = O_XRF + 2097152;        // int [4]
constexpr size_t O_IPOS  = O_CNT + 256;            // int [4][512] j -> pos

__device__ inline u16 f2b(float f) {
  union { float f; unsigned u; } v{f};
  return (u16)((v.u + 0x7FFFu + ((v.u >> 16) & 1u)) >> 16);
}
__device__ inline float b2f(u16 b) {
  union { unsigned u; float f; } v{(unsigned)b << 16};
  return v.f;
}
__device__ inline f32x4 MFMA(s16x8 a, s16x8 b, f32x4 c) {
  return __builtin_amdgcn_mfma_f32_16x16x32_bf16(a, b, c, 0, 0, 0);
}
__device__ inline f32x4 MFMAH(f16x8 a, f16x8 b, f32x4 c) {
  return __builtin_amdgcn_mfma_f32_16x16x32_f16(a, b, c, 0, 0, 0);
}
__device__ inline unsigned cvtpk(float lo, float hi) {
  unsigned r;
  asm("v_cvt_pk_bf16_f32 %0, %1, %2" : "=v"(r) : "v"(lo), "v"(hi));
  return r;
}
// packed f16 max on 32-bit carriers (ROCm 7.2 lacks __hmax2)
__device__ inline unsigned pkmax0(unsigned a) {
  unsigned d;
  asm("v_pk_max_f16 %0, %1, 0" : "=v"(d) : "v"(a));
  return d;
}

// ---------------- prep: xb + Wqkv^T + Wp2/packed + mask compaction ---------
__global__ __launch_bounds__(256) void prep_kernel(
    const float* __restrict__ x, const float* __restrict__ Wqkv,
    const float* __restrict__ Wp2,
    const float* __restrict__ Wp1, const float* __restrict__ bp1,
    const unsigned char* __restrict__ maskraw,
    u16* __restrict__ xb, u16* __restrict__ wqkvt, u16* __restrict__ wp2t,
    unsigned* __restrict__ packed, int* __restrict__ jidxg,
    int* __restrict__ cntg, int* __restrict__ iposg) {
  __shared__ int mode_max;
  __shared__ int mdec[2048];
  int blk = blockIdx.x, tid = threadIdx.x;
  if (blk < 256) {            // x -> xb
    for (int t = tid; t < 512; t += 256) {
      float4 v = ((const float4*)x)[blk * 512 + t];
      u16 o0 = f2b(v.x), o1 = f2b(v.y), o2 = f2b(v.z), o3 = f2b(v.w);
      u32x2 w; w.x = (unsigned)o0 | ((unsigned)o1 << 16);
      w.y = (unsigned)o2 | ((unsigned)o3 << 16);
      *(u32x2*)(xb + (size_t)(blk * 512 + t) * 4) = w;
    }
  } else if (blk < 352) {     // Wqkv^T
    int o0 = (blk - 256) * 2048;
    for (int t = tid; t < 2048; t += 256) {
      int o = o0 + t, n = o >> 8, k = o & 255;
      wqkvt[o] = f2b(Wqkv[k * 768 + n]);
    }
  } else if (blk == 352) {    // Wp2^T fp16 (padded) + half2-paired Wp1/bp1
    for (int t = tid; t < 4096; t += 256) {
      int h = t >> 8, c = t & 255;
      wp2t[t] = (h < 8) ? __half_as_ushort(__float2half(Wp2[c * 8 + h])) : (u16)0;
    }
    if (tid < 128) {
      int p = tid * 2;
      unsigned w0 = (unsigned)__half_as_ushort(__float2half(Wp1[p]))
                  | ((unsigned)__half_as_ushort(__float2half(Wp1[p + 1])) << 16);
      unsigned w1 = (unsigned)__half_as_ushort(__float2half(Wp1[256 + p]))
                  | ((unsigned)__half_as_ushort(__float2half(Wp1[256 + p + 1])) << 16);
      unsigned w2 = (unsigned)__half_as_ushort(__float2half(Wp1[512 + p]))
                  | ((unsigned)__half_as_ushort(__float2half(Wp1[512 + p + 1])) << 16);
      unsigned bb = (unsigned)__half_as_ushort(__float2half(bp1[p]))
                  | ((unsigned)__half_as_ushort(__float2half(bp1[p + 1])) << 16);
      uint4 o; o.x = w0; o.y = w1; o.z = w2; o.w = bb;
      ((uint4*)packed)[tid] = o;
    }
  } else {                    // mask decode (robust) + compaction + ipos
    if (tid == 0) mode_max = 0;
    __syncthreads();
    int lm = 0;
    for (int i = tid; i < CB*CN; i += 256)
      if ((i & 3) != 0) lm = max(lm, (int)maskraw[i]);
    atomicMax(&mode_max, lm);
    __syncthreads();
    int mv = mode_max;
    for (int i = tid; i < CB*CN; i += 256) {
      int val;
      if (mv == 0)      val = (((const int*)maskraw)[i] != 0);
      else if (mv == 1) val = (maskraw[i] != 0);
      else              val = (((const unsigned int*)maskraw)[i] != 0);
      mdec[i] = val;
    }
    __syncthreads();
    int w = tid >> 6, lane = tid & 63;
    if (w < 4) {              // wave w compacts batch b=w
      int b = w, basei = 0, basem = 0;
      for (int c = 0; c < 8; ++c) {
        int j = c * 64 + lane;
        int m = mdec[b * 512 + j];
        unsigned long long bal = __ballot(m != 0);
        int off  = __popcll(bal & ((1ull << lane) - 1ull));
        int offm = __popcll(~bal & ((1ull << lane) - 1ull));
        int pos;
        if (m) { pos = basei + off; jidxg[b * 512 + pos] = j; }
        else   { pos = 511 - (basem + offm); }
        iposg[b * 512 + j] = pos;
        basei += (int)__popcll(bal);
        basem += (int)(64 - __popcll(bal));
      }
      if (lane == 0) cntg[b] = basei;
      for (int p = basei + lane; p < 512; p += 64) jidxg[b * 512 + p] = 0;
    }
  }
}

// ---------------- merged qkv GEMM + pair-bias MLP + weight transposes ------
__global__ __launch_bounds__(256) void qkv_pbias_kernel(
    const u16* __restrict__ A, const u16* __restrict__ Wt,
    u16* __restrict__ qb, u16* __restrict__ kb, u16* __restrict__ vt,
    const float* __restrict__ pf, const unsigned* __restrict__ packed,
    const u16* __restrict__ wp2t, const float* __restrict__ bp2,
    const int* __restrict__ jidxg, const int* __restrict__ cntg,
    const int* __restrict__ iposg, u16* __restrict__ biasc,
    const float* __restrict__ Wout, const float* __restrict__ Wf1,
    const float* __restrict__ Wf2, u16* __restrict__ woutt,
    u16* __restrict__ wf1t, u16* __restrict__ wf2t) {
  __shared__ uint4 smem[1024];          // 16KB shared pool
  const int blk = blockIdx.x, tid = threadIdx.x;
  const int lane = tid & 63, w = tid >> 6;
  if (blk < 384) {
    u16* As = (u16*)smem;
    u16* Bs = (u16*)smem + 64 * 64;
    const int wm = w >> 1, wn = w & 1;
    const int bm = (blk / 12) * 64, bn = (blk % 12) * 64;
    f32x4 fz = {0.f, 0.f, 0.f, 0.f};
    f32x4 acc[2][2] = {{fz, fz}, {fz, fz}};
    for (int k0 = 0; k0 < 256; k0 += 64) {
#pragma unroll
      for (int t = tid; t < 512; t += 256) {
        int r = t >> 3, s = t & 7;
        s16x8 v = *(const s16x8*)(A + (size_t)(bm + r) * 256 + k0 + s * 8);
        *(s16x8*)(As + r * 64 + ((s ^ (r & 7)) << 3)) = v;
      }
#pragma unroll
      for (int t = tid; t < 512; t += 256) {
        int r = t >> 3, s = t & 7;
        s16x8 v = *(const s16x8*)(Wt + (size_t)(bn + r) * 256 + k0 + s * 8);
        *(s16x8*)(Bs + r * 64 + ((s ^ (r & 7)) << 3)) = v;
      }
      __syncthreads();
#pragma unroll
      for (int ks = 0; ks < 2; ++ks) {
        s16x8 af[2], bf[2];
#pragma unroll
        for (int mf = 0; mf < 2; ++mf) {
          int r = wm * 32 + mf * 16 + (lane & 15);
          int s = ks * 4 + (lane >> 4);
          af[mf] = *(const s16x8*)(As + r * 64 + ((s ^ (r & 7)) << 3));
        }
#pragma unroll
        for (int nf = 0; nf < 2; ++nf) {
          int r = wn * 32 + nf * 16 + (lane & 15);
          int s = ks * 4 + (lane >> 4);
          bf[nf] = *(const s16x8*)(Bs + r * 64 + ((s ^ (r & 7)) << 3));
        }
#pragma unroll
        for (int mf = 0; mf < 2; ++mf)
#pragma unroll
          for (int nf = 0; nf < 2; ++nf)
            acc[mf][nf] = MFMA(af[mf], bf[nf], acc[mf][nf]);
      }
      __syncthreads();
    }
#pragma unroll
    for (int mf = 0; mf < 2; ++mf) {
#pragma unroll
      for (int nf = 0; nf < 2; ++nf) {
#pragma unroll
        for (int r = 0; r < 4; ++r) {
          int m = bm + wm * 32 + mf * 16 + (lane >> 4) * 4 + r;
          int n = bn + wn * 32 + nf * 16 + (lane & 15);
          float v = acc[mf][nf][r];
          if (n < 256) {
            qb[(size_t)m * 256 + n] = f2b(v * QSCALE);
          } else if (n < 512) {
            kb[(size_t)m * 256 + (n - 256)] = f2b(v);
          } else {
            int nv = n - 512, h = nv >> 5, d = nv & 31;
            int bb = m >> 9, j = m & 511;
            int pos = iposg[bb * 512 + j];
            vt[(size_t)((bb * 8 + h) * 32 + d) * 512 + pos] = f2b(v);
          }
        }
      }
    }
  } else if (blk < 2432) {
    uint4* pk = smem;                   // 128 x {w0,w1,w2,b} half2 (2KB)
    float* pfl = (float*)(smem + 128);  // 1536 floats (6KB)
    int* ji = (int*)(smem + 512);       // 512 ints (2KB)
    const int bid = blk - 384;          // b*512 + i
    const int b = bid >> 9, i = bid & 511;
    const int q = lane >> 4, hr = lane & 15;
    if (tid < 128) pk[tid] = ((const uint4*)packed)[tid];
    const float4* pfr = (const float4*)(pf + (size_t)(b * 512 + i) * 1536);
#pragma unroll
    for (int t = tid; t < 384; t += 256) ((float4*)pfl)[t] = pfr[t];
    for (int t = tid; t < 512; t += 256) ji[t] = jidxg[b * 512 + t];
    const int cnt = cntg[b];
    __syncthreads();
    __half2 f0d[8], f1d[8], f2d[8];
#pragma unroll
    for (int t = 0; t < 8; ++t) {
      int g = t * 4 + w;                // round-robin group
      if (g * 16 < cnt) {
        int jsrc = ji[g * 16 + hr];
        f0d[t] = __float2half2_rn(pfl[jsrc * 3 + 0]);
        f1d[t] = __float2half2_rn(pfl[jsrc * 3 + 1]);
        f2d[t] = __float2half2_rn(pfl[jsrc * 3 + 2]);
      }
    }
    f32x4 fz = {0.f, 0.f, 0.f, 0.f};
    f32x4 acc[8] = {fz, fz, fz, fz, fz, fz, fz, fz};
    for (int chunk = 0; chunk < 8; ++chunk) {
      f16x8 wfrag = *(const f16x8*)(wp2t + hr * 256 + chunk * 32 + q * 8);
      int pbase = chunk * 16 + q * 4;
      __half2 w0[4], w1[4], w2[4], bb[4];
#pragma unroll
      for (int p = 0; p < 4; ++p) {
        uint4 c = pk[pbase + p];
        w0[p] = *(const __half2*)&c.x;
        w1[p] = *(const __half2*)&c.y;
        w2[p] = *(const __half2*)&c.z;
        bb[p] = *(const __half2*)&c.w;
      }
#pragma unroll
      for (int t = 0; t < 8; ++t) {
        int g = t * 4 + w;
        if (g * 16 < cnt) {             // wave-uniform tile guard
          union { unsigned u[4]; f16x8 v; } af;
#pragma unroll
          for (int p = 0; p < 4; ++p) {
            __half2 h = __hfma2(f0d[t], w0[p], bb[p]);
            h = __hfma2(f1d[t], w1[p], h);
            h = __hfma2(f2d[t], w2[p], h);
            af.u[p] = pkmax0(*(const unsigned*)&h);
          }
          acc[t] = MFMAH(af.v, wfrag, acc[t]);
        }
      }
    }
    if (hr < 8) {
      float bb = bp2[hr];
      size_t base = ((size_t)(b * 8 + hr) * 512 + i) * 512;
#pragma unroll
      for (int t = 0; t < 8; ++t) {
        int g = t * 4 + w;
        if (g * 16 < cnt) {
          int p0 = g * 16 + q * 4;
          u32x2 o;
          o.x = cvtpk(acc[t][0] + bb, acc[t][1] + bb);
          o.y = cvtpk(acc[t][2] + bb, acc[t][3] + bb);
          *(u32x2*)(biasc + base + p0) = o;
        }
      }
    }
  } else if (blk < 2464) {    // Wout^T
    int o0 = (blk - 2432) * 2048;
    for (int t = tid; t < 2048; t += 256) {
      int o = o0 + t, n = o >> 8, k = o & 255;
      woutt[o] = f2b(Wout[k * 256 + n]);
    }
  } else if (blk < 2592) {    // Wf1^T
    int o0 = (blk - 2464) * 2048;
    for (int t = tid; t < 2048; t += 256) {
      int o = o0 + t, n = o >> 8, k = o & 255;
      wf1t[o] = f2b(Wf1[k * 1024 + n]);
    }
  } else {                    // Wf2^T
    int o0 = (blk - 2592) * 2048;
    for (int t = tid; t < 2048; t += 256) {
      int o = o0 + t, n = o >> 10, k = o & 1023;
      wf2t[o] = f2b(Wf2[k * 256 + n]);
    }
  }
}

// ---------------- fused flash attention: compacted keys, 8 waves -----------
__global__ __launch_bounds__(512) void flash_kernel(
    const u16* __restrict__ qb, const u16* __restrict__ kb,
    const u16* __restrict__ vt, const u16* __restrict__ biasc,
    const int* __restrict__ jidxg, const int* __restrict__ cntg,
    u16* __restrict__ aout) {
  const int i0 = blockIdx.x * 64, h = blockIdx.y, b = blockIdx.z;
  const int tid = threadIdx.x;
  const int lane = tid & 63, w = tid >> 6;
  const int mf = w & 3, jhalf = w >> 2;
  __shared__ u16 qs[64 * 32];
  __shared__ u16 ksh[128 * 32];
  __shared__ u16 vs[32 * 128];
  __shared__ u16 ps[8][16 * 64];
  __shared__ float cmb[4][2][16][2];
  __shared__ int ji[512];
  for (int t = tid; t < 512; t += 512) ji[t] = jidxg[b * 512 + t];
  for (int t = tid; t < 256; t += 512) {
    int r = t >> 2, s = t & 3;
    s16x8 v = *(const s16x8*)(qb + (size_t)(b * 512 + i0 + r) * 256 + h * 32 + s * 8);
    *(s16x8*)(qs + r * 32 + ((s ^ (r & 3)) << 3)) = v;
  }
  const int cnt = cntg[b];
  __syncthreads();
  f32x4 fz = {0.f, 0.f, 0.f, 0.f};
  f32x4 oacc[2] = {fz, fz};
  float mrun[4] = {-3e38f, -3e38f, -3e38f, -3e38f};
  float lrun[4] = {0.f, 0.f, 0.f, 0.f};
  const int jj0 = jhalf * 64;
  const int il = mf * 16 + (lane >> 4) * 4;
  const u16* bbase = biasc + ((size_t)((b * 8 + h) * 512 + i0 + il)) * 512
                   + jj0 + (lane & 15);
  const int NJT = (cnt + 127) >> 7;
  for (int jc = 0; jc < NJT; ++jc) {
    int j0 = jc * 128;
    {  // K tile (row gather via jidx)
      int r = tid >> 2, s = tid & 3;
      int jsrc = ji[j0 + r];
      s16x8 v = *(const s16x8*)(kb + (size_t)(b * 512 + jsrc) * 256 + h * 32 + s * 8);
      *(s16x8*)(ksh + r * 32 + ((s ^ (r & 3)) << 3)) = v;
    }
    {  // V tile (pos-contiguous vector load + vector swizzled store)
      int r = tid >> 4, s = tid & 15;
      s16x8 v = *(const s16x8*)(vt + (size_t)((b * 8 + h) * 32 + r) * 512 + j0 + s * 8);
      *(s16x8*)(vs + r * 128 + (((s & 8) | ((s & 7) ^ (r & 7))) << 3)) = v;
    }
    u16 bvr[4][4];
#pragma unroll
    for (int jf = 0; jf < 4; ++jf)
#pragma unroll
      for (int r = 0; r < 4; ++r)
        bvr[jf][r] = bbase[(size_t)r * 512 + j0 + jf * 16];
    __syncthreads();
    int mk[4];
#pragma unroll
    for (int jf = 0; jf < 4; ++jf)
      mk[jf] = (j0 + jj0 + jf * 16 + (lane & 15)) < cnt;
    int arow = mf * 16 + (lane & 15);
    s16x8 af = *(const s16x8*)(qs + arow * 32 + (((lane >> 4) ^ (arow & 3)) << 3));
    f32x4 sm[4];
#pragma unroll
    for (int jf = 0; jf < 4; ++jf) {
      int brow = jj0 + jf * 16 + (lane & 15);
      s16x8 bfr = *(const s16x8*)(ksh + brow * 32 + (((lane >> 4) ^ (brow & 3)) << 3));
      sm[jf] = MFMA(af, bfr, fz);
    }
#pragma unroll
    for (int jf = 0; jf < 4; ++jf) {
#pragma unroll
      for (int r = 0; r < 4; ++r) {
        float sval = sm[jf][r] + b2f(bvr[jf][r]);
        sm[jf][r] = mk[jf] ? sval : -1e9f;
      }
    }
    float mx[4];
#pragma unroll
    for (int r = 0; r < 4; ++r)
      mx[r] = fmaxf(fmaxf(sm[0][r], sm[1][r]), fmaxf(sm[2][r], sm[3][r]));
#pragma unroll
    for (int d = 1; d < 16; d <<= 1)
#pragma unroll
      for (int r = 0; r < 4; ++r) mx[r] = fmaxf(mx[r], __shfl_xor(mx[r], d));
    float psl[4] = {0.f, 0.f, 0.f, 0.f};
#pragma unroll
    for (int jf = 0; jf < 4; ++jf)
#pragma unroll
      for (int r = 0; r < 4; ++r) {
        float p = __expf(sm[jf][r] - mx[r]);
        sm[jf][r] = p; psl[r] += p;
      }
#pragma unroll
    for (int d = 1; d < 16; d <<= 1)
#pragma unroll
      for (int r = 0; r < 4; ++r) psl[r] += __shfl_xor(psl[r], d);
    if ((lane & 15) == 0) {
#pragma unroll
      for (int r = 0; r < 4; ++r) {
        int row = (lane >> 4) * 4 + r;
        cmb[mf][jhalf][row][0] = mx[r];
        cmb[mf][jhalf][row][1] = psl[r];
      }
    }
    __syncthreads();
    float selfs[4];
#pragma unroll
    for (int r = 0; r < 4; ++r) {
      int row = (lane >> 4) * 4 + r;
      float omx = cmb[mf][1 - jhalf][row][0];
      float ops = cmb[mf][1 - jhalf][row][1];
      float tm = fmaxf(mx[r], omx);
      float nm = fmaxf(mrun[r], tm);
      float sc = __expf(mrun[r] - nm);
      selfs[r] = __expf(mx[r] - nm);
      float ptile = psl[r] * selfs[r] + ops * __expf(omx - nm);
      lrun[r] = lrun[r] * sc + ptile;
      mrun[r] = nm;
      oacc[0][r] *= sc; oacc[1][r] *= sc;
    }
    u16* pw = &ps[w][0];
#pragma unroll
    for (int jf = 0; jf < 4; ++jf) {
      int jcol = jf * 16 + (lane & 15);
      int slot = jcol >> 3, el = jcol & 7;
#pragma unroll
      for (int r = 0; r < 4; ++r) {
        int row = (lane >> 4) * 4 + r;
        pw[row * 64 + ((slot ^ (row & 7)) << 3) + el] = f2b(sm[jf][r] * selfs[r]);
      }
    }
#pragma unroll
    for (int kw = 0; kw < 2; ++kw) {
      int prow = lane & 15;
      s16x8 pa = *(const s16x8*)(pw + prow * 64 + (((kw * 4 + (lane >> 4)) ^ (prow & 7)) << 3));
#pragma unroll
      for (int df = 0; df < 2; ++df) {
        int drow = df * 16 + (lane & 15);
        int jcol = jj0 + kw * 32 + ((lane >> 4) << 3);
        int slot = jcol >> 3;
        s16x8 vv = *(const s16x8*)(vs + drow * 128 + (((slot & 8) | ((slot & 7) ^ (drow & 7))) << 3));
        oacc[df] = MFMA(pa, vv, oacc[df]);
      }
    }
    __syncthreads();
  }
  float* obuf = (float*)&ps[0][0];
  if (jhalf == 1) {
#pragma unroll
    for (int r = 0; r < 4; ++r) {
      int row = mf * 16 + (lane >> 4) * 4 + r;
#pragma unroll
      for (int df = 0; df < 2; ++df)
        obuf[row * 33 + df * 16 + (lane & 15)] = oacc[df][r];
    }
  }
  __syncthreads();
  if (jhalf == 0) {
#pragma unroll
    for (int r = 0; r < 4; ++r) {
      float inv = 1.0f / lrun[r];
      int row = mf * 16 + (lane >> 4) * 4 + r;
      int i = i0 + row;
#pragma unroll
      for (int df = 0; df < 2; ++df) {
        int d = df * 16 + (lane & 15);
        float o = (oacc[df][r] + obuf[row * 33 + d]) * inv;
        aout[(size_t)(b * 512 + i) * 256 + h * 32 + d] = f2b(o);
      }
    }
  }
}

// ---------------- T1: outproj + bout + residual(x) + LN1 -> x1b + xrf ------
// Full-row blocks: BM=16, BN=256, grid 128, 256 thr (4 waves x 64 cols).
__global__ __launch_bounds__(256) void gemm_ln1_kernel(
    const u16* __restrict__ A, const u16* __restrict__ Wt,
    const float* __restrict__ bias, const float* __restrict__ x,
    const float* __restrict__ g1, const float* __restrict__ b1,
    u16* __restrict__ x1b, float* __restrict__ xrf) {
  __shared__ u16 As[16 * 64];
  __shared__ u16 Bs[256 * 64];
  __shared__ float part[16][4][2];
  __shared__ float rowm[16], rowr[16];
  const int tid = threadIdx.x;
  const int lane = tid & 63, w = tid >> 6;
  const int bm = blockIdx.x * 16;
  f32x4 fz = {0.f, 0.f, 0.f, 0.f};
  f32x4 acc[4] = {fz, fz, fz, fz};
  for (int k0 = 0; k0 < 256; k0 += 64) {
    if (tid < 128) {
      int r = tid >> 3, s = tid & 7;
      s16x8 v = *(const s16x8*)(A + (size_t)(bm + r) * 256 + k0 + s * 8);
      *(s16x8*)(As + r * 64 + ((s ^ (r & 7)) << 3)) = v;
    }
#pragma unroll
    for (int t = tid; t < 2048; t += 256) {
      int r = t >> 3, s = t & 7;
      s16x8 v = *(const s16x8*)(Wt + (size_t)r * 256 + k0 + s * 8);
      *(s16x8*)(Bs + r * 64 + ((s ^ (r & 7)) << 3)) = v;
    }
    __syncthreads();
#pragma unroll
    for (int ks = 0; ks < 2; ++ks) {
      int ar = lane & 15, as = ks * 4 + (lane >> 4);
      s16x8 af = *(const s16x8*)(As + ar * 64 + ((as ^ (ar & 7)) << 3));
#pragma unroll
      for (int nf = 0; nf < 4; ++nf) {
        int br = w * 64 + nf * 16 + (lane & 15);
        s16x8 bf = *(const s16x8*)(Bs + br * 64 + ((as ^ (br & 7)) << 3));
        acc[nf] = MFMA(af, bf, acc[nf]);
      }
    }
    __syncthreads();
  }
  // epilogue: v = acc + bias + x, then LN1 via cross-wave reduce
  float v[4][4];
  float sp[4] = {0.f, 0.f, 0.f, 0.f}, ssp[4] = {0.f, 0.f, 0.f, 0.f};
#pragma unroll
  for (int nf = 0; nf < 4; ++nf) {
    int col = w * 64 + nf * 16 + (lane & 15);
#pragma unroll
    for (int r = 0; r < 4; ++r) {
      int row = (lane >> 4) * 4 + r;
      float val = acc[nf][r] + bias[col] + x[(size_t)(bm + row) * 256 + col];
      v[nf][r] = val;
      sp[r] += val; ssp[r] += val * val;
    }
  }
#pragma unroll
  for (int d = 1; d < 16; d <<= 1)
#pragma unroll
    for (int r = 0; r < 4; ++r) {
      sp[r]  += __shfl_xor(sp[r], d);
      ssp[r] += __shfl_xor(ssp[r], d);
    }
  if ((lane & 15) == 0) {
#pragma unroll
    for (int r = 0; r < 4; ++r) {
      int row = (lane >> 4) * 4 + r;
      part[row][w][0] = sp[r];
      part[row][w][1] = ssp[r];
    }
  }
  __syncthreads();
  if (tid < 16) {
    float s = part[tid][0][0] + part[tid][1][0] + part[tid][2][0] + part[tid][3][0];
    float ss = part[tid][0][1] + part[tid][1][1] + part[tid][2][1] + part[tid][3][1];
    float mean = s * (1.0f / 256.0f);
    float var  = ss * (1.0f / 256.0f) - mean * mean;
    rowm[tid] = mean; rowr[tid] = rsqrtf(var + CEPS);
  }
  __syncthreads();
#pragma unroll
  for (int nf = 0; nf < 4; ++nf) {
    int col = w * 64 + nf * 16 + (lane & 15);
#pragma unroll
    for (int r = 0; r < 4; ++r) {
      int row = (lane >> 4) * 4 + r;
      float xr = (v[nf][r] - rowm[row]) * rowr[row] * g1[col] + b1[col];
      xrf[(size_t)(bm + row) * 256 + col] = xr;
      x1b[(size_t)(bm + row) * 256 + col] = f2b(xr);
    }
  }
}

// ---------------- T2: FFN1 plain: x1b @ wf1t + bf1 -> GELU -> h1b ----------
__global__ __launch_bounds__(256) void ffn1_kernel(
    const u16* __restrict__ A, const u16* __restrict__ Wt,
    const float* __restrict__ bias, u16* __restrict__ outb) {
  __shared__ u16 As[64 * 64];
  __shared__ u16 Bs[64 * 64];
  const int tid = threadIdx.x;
  const int lane = tid & 63, w = tid >> 6;
  const int wm = w >> 1, wn = w & 1;
  const int bm = blockIdx.y * 64, bn = blockIdx.x * 64;
  f32x4 fz = {0.f, 0.f, 0.f, 0.f};
  f32x4 acc[2][2] = {{fz, fz}, {fz, fz}};
  for (int k0 = 0; k0 < 256; k0 += 64) {
#pragma unroll
    for (int t = tid; t < 512; t += 256) {
      int r = t >> 3, s = t & 7;
      s16x8 v = *(const s16x8*)(A + (size_t)(bm + r) * 256 + k0 + s * 8);
      *(s16x8*)(As + r * 64 + ((s ^ (r & 7)) << 3)) = v;
    }
#pragma unroll
    for (int t = tid; t < 512; t += 256) {
      int r = t >> 3, s = t & 7;
      s16x8 v = *(const s16x8*)(Wt + (size_t)(bn + r) * 256 + k0 + s * 8);
      *(s16x8*)(Bs + r * 64 + ((s ^ (r & 7)) << 3)) = v;
    }
    __syncthreads();
#pragma unroll
    for (int ks = 0; ks < 2; ++ks) {
      s16x8 af[2], bf[2];
#pragma unroll
      for (int mf = 0; mf < 2; ++mf) {
        int r = wm * 32 + mf * 16 + (lane & 15);
        int s = ks * 4 + (lane >> 4);
        af[mf] = *(const s16x8*)(As + r * 64 + ((s ^ (r & 7)) << 3));
      }
#pragma unroll
      for (int nf = 0; nf < 2; ++nf) {
        int r = wn * 32 + nf * 16 + (lane & 15);
        int s = ks * 4 + (lane >> 4);
        bf[nf] = *(const s16x8*)(Bs + r * 64 + ((s ^ (r & 7)) << 3));
      }
#pragma unroll
      for (int mf = 0; mf < 2; ++mf)
#pragma unroll
        for (int nf = 0; nf < 2; ++nf)
          acc[mf][nf] = MFMA(af[mf], bf[nf], acc[mf][nf]);
    }
    __syncthreads();
  }
#pragma unroll
  for (int mf = 0; mf < 2; ++mf) {
#pragma unroll
    for (int nf = 0; nf < 2; ++nf) {
#pragma unroll
      for (int r = 0; r < 4; ++r) {
        int m = bm + wm * 32 + mf * 16 + (lane >> 4) * 4 + r;
        int n = bn + wn * 32 + nf * 16 + (lane & 15);
        float gv = acc[mf][nf][r] + bias[n];
        gv = 0.5f * gv * (1.0f + erff(gv * 0.70710678118654752f));
        outb[(size_t)m * 1024 + n] = f2b(gv);
      }
    }
  }
}

// ---------------- T3: FFN2 + bf2 + xrf residual + LN2 -> out ---------------
// Full-row blocks: BM=16, BN=256, K=1024, grid 128, 256 thr.
__global__ __launch_bounds__(256) void gemm_ln2_kernel(
    const u16* __restrict__ A, const u16* __restrict__ Wt,
    const float* __restrict__ bias, const float* __restrict__ xrf,
    const float* __restrict__ g2, const float* __restrict__ b2,
    float* __restrict__ out) {
  __shared__ u16 As[16 * 64];
  __shared__ u16 Bs[256 * 64];
  __shared__ float part[16][4][2];
  __shared__ float rowm[16], rowr[16];
  const int tid = threadIdx.x;
  const int lane = tid & 63, w = tid >> 6;
  const int bm = blockIdx.x * 16;
  f32x4 fz = {0.f, 0.f, 0.f, 0.f};
  f32x4 acc[4] = {fz, fz, fz, fz};
  for (int k0 = 0; k0 < 1024; k0 += 64) {
    if (tid < 128) {
      int r = tid >> 3, s = tid & 7;
      s16x8 v = *(const s16x8*)(A + (size_t)(bm + r) * 1024 + k0 + s * 8);
      *(s16x8*)(As + r * 64 + ((s ^ (r & 7)) << 3)) = v;
    }
#pragma unroll
    for (int t = tid; t < 2048; t += 256) {
      int r = t >> 3, s = t & 7;
      s16x8 v = *(const s16x8*)(Wt + (size_t)r * 1024 + k0 + s * 8);
      *(s16x8*)(Bs + r * 64 + ((s ^ (r & 7)) << 3)) = v;
    }
    __syncthreads();
#pragma unroll
    for (int ks = 0; ks < 2; ++ks) {
      int ar = lane & 15, as = ks * 4 + (lane >> 4);
      s16x8 af = *(const s16x8*)(As + ar * 64 + ((as ^ (ar & 7)) << 3));
#pragma unroll
      for (int nf = 0; nf < 4; ++nf) {
        int br = w * 64 + nf * 16 + (lane & 15);
        s16x8 bf = *(const s16x8*)(Bs + br * 64 + ((as ^ (br & 7)) << 3));
        acc[nf] = MFMA(af, bf, acc[nf]);
      }
    }
    __syncthreads();
  }
  float v[4][4];
  float sp[4] = {0.f, 0.f, 0.f, 0.f}, ssp[4] = {0.f, 0.f, 0.f, 0.f};
#pragma unroll
  for (int nf = 0; nf < 4; ++nf) {
    int col = w * 64 + nf * 16 + (lane & 15);
#pragma unroll
    for (int r = 0; r < 4; ++r) {
      int row = (lane >> 4) * 4 + r;
      float val = acc[nf][r] + bias[col] + xrf[(size_t)(bm + row) * 256 + col];
      v[nf][r] = val;
      sp[r] += val; ssp[r] += val * val;
    }
  }
#pragma unroll
  for (int d = 1; d < 16; d <<= 1)
#pragma unroll
    for (int r = 0; r < 4; ++r) {
      sp[r]  += __shfl_xor(sp[r], d);
      ssp[r] += __shfl_xor(ssp[r], d);
    }
  if ((lane & 15) == 0) {
#pragma unroll
    for (int r = 0; r < 4; ++r) {
      int row = (lane >> 4) * 4 + r;
      part[row][w][0] = sp[r];
      part[row][w][1] = ssp[r];
    }
  }
  __syncthreads();
  if (tid < 16) {
    float s = part[tid][0][0] + part[tid][1][0] + part[tid][2][0] + part[tid][3][0];
    float ss = part[tid][0][1] + part[tid][1][1] + part[tid][2][1] + part[tid][3][1];
    float mean = s * (1.0f / 256.0f);
    float var  = ss * (1.0f / 256.0f) - mean * mean;
    rowm[tid] = mean; rowr[tid] = rsqrtf(var + CEPS);
  }
  __syncthreads();
#pragma unroll
  for (int nf = 0; nf < 4; ++nf) {
    int col = w * 64 + nf * 16 + (lane & 15);
#pragma unroll
    for (int r = 0; r < 4; ++r) {
      int row = (lane >> 4) * 4 + r;
      out[(size_t)(bm + row) * 256 + col] =
          (v[nf][r] - rowm[row]) * rowr[row] * g2[col] + b2[col];
    }
  }
}

extern "C" void kernel_launch(void* const* d_in, const int* in_sizes, int n_in,
                              void* d_out, int out_size, void* d_ws, size_t ws_size,
                              hipStream_t stream) {
  (void)in_sizes; (void)n_in; (void)out_size; (void)ws_size;
  const float* x    = (const float*)d_in[0];
  const void*  mask = d_in[1];
  const float* pf   = (const float*)d_in[2];
  const float* Wqkv = (const float*)d_in[3];
  const float* Wout = (const float*)d_in[4];
  const float* bout = (const float*)d_in[5];
  const float* Wp1  = (const float*)d_in[6];
  const float* bp1  = (const float*)d_in[7];
  const float* Wp2  = (const float*)d_in[8];
  const float* bp2  = (const float*)d_in[9];
  const float* Wf1  = (const float*)d_in[10];
  const float* bf1  = (const float*)d_in[11];
  const float* Wf2  = (const float*)d_in[12];
  const float* bf2  = (const float*)d_in[13];
  const float* g1   = (const float*)d_in[14];
  const float* b1   = (const float*)d_in[15];
  const float* g2   = (const float*)d_in[16];
  const float* b2   = (const float*)d_in[17];

  char* ws = (char*)d_ws;
  u16* xb     = (u16*)(ws + O_XB);
  u16* qb     = (u16*)(ws + O_QB);
  u16* kb     = (u16*)(ws + O_KB);
  u16* vt     = (u16*)(ws + O_VT);
  u16* wqkvt  = (u16*)(ws + O_WQKVT);
  u16* woutt  = (u16*)(ws + O_WOUTT);
  u16* wf1t   = (u16*)(ws + O_WF1T);
  u16* wf2t   = (u16*)(ws + O_WF2T);
  u16* wp2t   = (u16*)(ws + O_WP2T);
  unsigned* packed = (unsigned*)(ws + O_PACKED);
  int* jidxg  = (int*)(ws + O_JIDX);
  int* cntg   = (int*)(ws + O_CNT);
  int* iposg  = (int*)(ws + O_IPOS);
  u16* biasc  = (u16*)(ws + O_BIAS);
  u16* aout   = (u16*)(ws + O_AOUT);
  u16* h1b    = (u16*)(ws + O_H1B);
  u16* x1b    = (u16*)(ws + O_X1B);
  float* xrf  = (float*)(ws + O_XRF);
  float* out  = (float*)d_out;

  hipLaunchKernelGGL(prep_kernel, dim3(354), dim3(256), 0, stream,
                     x, Wqkv, Wp2, Wp1, bp1,
                     (const unsigned char*)mask,
                     xb, wqkvt, wp2t, packed, jidxg, cntg, iposg);
  // merged: qkv (384) + pbias (2048) + Wout/Wf1/Wf2 transposes (288)
  hipLaunchKernelGGL(qkv_pbias_kernel, dim3(2720), dim3(256), 0, stream,
                     xb, wqkvt, qb, kb, vt,
                     pf, packed, wp2t, bp2, jidxg, cntg, iposg, biasc,
                     Wout, Wf1, Wf2, woutt, wf1t, wf2t);
  // fused attention (compacted keys, pos-space V)
  hipLaunchKernelGGL(flash_kernel, dim3(8, 8, 4), dim3(512), 0, stream,
                     qb, kb, vt, biasc, jidxg, cntg, aout);
  // T1: outproj + bout + residual(x) + LN1 -> x1b + xrf
  hipLaunchKernelGGL(gemm_ln1_kernel, dim3(128), dim3(256), 0, stream,
                     aout, woutt, bout, x, g1, b1, x1b, xrf);
  // T2: FFN1 + GELU -> h1b
  hipLaunchKernelGGL(ffn1_kernel, dim3(16, 32), dim3(256), 0, stream,
                     x1b, wf1t, bf1, h1b);
  // T3: FFN2 + bf2 + xrf + LN2 -> out
  hipLaunchKernelGGL(gemm_ln2_kernel, dim3(128), dim3(256), 0, stream,
                     h1b, wf2t, bf2, xrf, g2, b2, out);
}

// Round 22
// 94.611 us; speedup vs baseline: 1.1007x; 1.1007x over previous
//
#include <hip/hip_runtime.h>
#include <hip/hip_fp16.h>
#include <math.h>

typedef unsigned short u16;
typedef short s16x8 __attribute__((ext_vector_type(8)));
typedef _Float16 f16x8 __attribute__((ext_vector_type(8)));
typedef float f32x4 __attribute__((ext_vector_type(4)));
typedef unsigned int u32x2 __attribute__((ext_vector_type(2)));

constexpr int CB = 4, CN = 512, CD = 256, CH = 8, CHD = 32;
constexpr float CEPS = 1e-5f;
constexpr int M_ROWS = CB * CN; // 2048
constexpr float QSCALE = 0.17677669529663687f; // 32^-0.5

// ---- workspace layout (byte offsets) ----
constexpr size_t O_XB    = 0;                      // u16 [2048][256]
constexpr size_t O_QB    = 1048576;                // u16 [2048][256] (pre-scaled)
constexpr size_t O_KB    = 2097152;                // u16 [2048][256]
constexpr size_t O_VT    = 3145728;                // u16 [4][8][32][512] pos-space
constexpr size_t O_WQKVT = 4194304;                // u16 [768][256]
constexpr size_t O_WOUTT = O_WQKVT + 393216;       // u16 [256][256]
constexpr size_t O_WF1T  = O_WOUTT + 131072;       // u16 [1024][256]
constexpr size_t O_WF2T  = O_WF1T + 524288;        // u16 [256][1024]
constexpr size_t O_WP2T  = O_WF2T + 524288;        // fp16 [16][256] (pad h>=8 = 0)
constexpr size_t O_PACKED= O_WP2T + 8192;          // u32 [128 pairs][4] half2 {w0,w1,w2,b}
constexpr size_t O_JIDX  = O_PACKED + 4096;        // int [4][512] compacted j indices
constexpr size_t O_BIAS  = O_JIDX + 8192;          // u16 [4][8][512][512] bf16 (pos-space)
constexpr size_t O_AOUT  = O_BIAS + 16777216;      // u16 [2048][256]
constexpr size_t O_H1B   = O_AOUT + 1048576;       // u16 [2048][1024]
constexpr size_t O_PRE1  = O_H1B + 4194304;        // f32 [2048][256]
constexpr size_t O_PRE2  = O_PRE1 + 2097152;       // f32 [2048][256]
constexpr size_t O_CNT   = O_PRE2 + 2097152;       // int [4]
constexpr size_t O_IPOS  = O_CNT + 256;            // int [4][512] j -> pos

__device__ inline u16 f2b(float f) {
  union { float f; unsigned u; } v{f};
  return (u16)((v.u + 0x7FFFu + ((v.u >> 16) & 1u)) >> 16);
}
__device__ inline float b2f(u16 b) {
  union { unsigned u; float f; } v{(unsigned)b << 16};
  return v.f;
}
__device__ inline f32x4 MFMA(s16x8 a, s16x8 b, f32x4 c) {
  return __builtin_amdgcn_mfma_f32_16x16x32_bf16(a, b, c, 0, 0, 0);
}
__device__ inline f32x4 MFMAH(f16x8 a, f16x8 b, f32x4 c) {
  return __builtin_amdgcn_mfma_f32_16x16x32_f16(a, b, c, 0, 0, 0);
}
__device__ inline unsigned cvtpk(float lo, float hi) {
  unsigned r;
  asm("v_cvt_pk_bf16_f32 %0, %1, %2" : "=v"(r) : "v"(lo), "v"(hi));
  return r;
}
// packed f16 max on 32-bit carriers (ROCm 7.2 lacks __hmax2)
__device__ inline unsigned pkmax0(unsigned a) {
  unsigned d;
  asm("v_pk_max_f16 %0, %1, 0" : "=v"(d) : "v"(a));
  return d;
}

// ---------------- prep: xb + Wqkv^T + Wp2/packed + mask compaction ---------
__global__ __launch_bounds__(256) void prep_kernel(
    const float* __restrict__ x, const float* __restrict__ Wqkv,
    const float* __restrict__ Wp2,
    const float* __restrict__ Wp1, const float* __restrict__ bp1,
    const unsigned char* __restrict__ maskraw,
    u16* __restrict__ xb, u16* __restrict__ wqkvt, u16* __restrict__ wp2t,
    unsigned* __restrict__ packed, int* __restrict__ jidxg,
    int* __restrict__ cntg, int* __restrict__ iposg) {
  __shared__ int mode_max;
  __shared__ int mdec[2048];
  int blk = blockIdx.x, tid = threadIdx.x;
  if (blk < 256) {            // x -> xb
    for (int t = tid; t < 512; t += 256) {
      float4 v = ((const float4*)x)[blk * 512 + t];
      u16 o0 = f2b(v.x), o1 = f2b(v.y), o2 = f2b(v.z), o3 = f2b(v.w);
      u32x2 w; w.x = (unsigned)o0 | ((unsigned)o1 << 16);
      w.y = (unsigned)o2 | ((unsigned)o3 << 16);
      *(u32x2*)(xb + (size_t)(blk * 512 + t) * 4) = w;
    }
  } else if (blk < 352) {     // Wqkv^T
    int o0 = (blk - 256) * 2048;
    for (int t = tid; t < 2048; t += 256) {
      int o = o0 + t, n = o >> 8, k = o & 255;
      wqkvt[o] = f2b(Wqkv[k * 768 + n]);
    }
  } else if (blk == 352) {    // Wp2^T fp16 (padded) + half2-paired Wp1/bp1
    for (int t = tid; t < 4096; t += 256) {
      int h = t >> 8, c = t & 255;
      wp2t[t] = (h < 8) ? __half_as_ushort(__float2half(Wp2[c * 8 + h])) : (u16)0;
    }
    if (tid < 128) {
      int p = tid * 2;
      unsigned w0 = (unsigned)__half_as_ushort(__float2half(Wp1[p]))
                  | ((unsigned)__half_as_ushort(__float2half(Wp1[p + 1])) << 16);
      unsigned w1 = (unsigned)__half_as_ushort(__float2half(Wp1[256 + p]))
                  | ((unsigned)__half_as_ushort(__float2half(Wp1[256 + p + 1])) << 16);
      unsigned w2 = (unsigned)__half_as_ushort(__float2half(Wp1[512 + p]))
                  | ((unsigned)__half_as_ushort(__float2half(Wp1[512 + p + 1])) << 16);
      unsigned bb = (unsigned)__half_as_ushort(__float2half(bp1[p]))
                  | ((unsigned)__half_as_ushort(__float2half(bp1[p + 1])) << 16);
      uint4 o; o.x = w0; o.y = w1; o.z = w2; o.w = bb;
      ((uint4*)packed)[tid] = o;
    }
  } else {                    // mask decode (robust) + compaction + ipos
    if (tid == 0) mode_max = 0;
    __syncthreads();
    int lm = 0;
    for (int i = tid; i < CB*CN; i += 256)
      if ((i & 3) != 0) lm = max(lm, (int)maskraw[i]);
    atomicMax(&mode_max, lm);
    __syncthreads();
    int mv = mode_max;
    for (int i = tid; i < CB*CN; i += 256) {
      int val;
      if (mv == 0)      val = (((const int*)maskraw)[i] != 0);
      else if (mv == 1) val = (maskraw[i] != 0);
      else              val = (((const unsigned int*)maskraw)[i] != 0);
      mdec[i] = val;
    }
    __syncthreads();
    int w = tid >> 6, lane = tid & 63;
    if (w < 4) {              // wave w compacts batch b=w
      int b = w, basei = 0, basem = 0;
      for (int c = 0; c < 8; ++c) {
        int j = c * 64 + lane;
        int m = mdec[b * 512 + j];
        unsigned long long bal = __ballot(m != 0);
        int off  = __popcll(bal & ((1ull << lane) - 1ull));
        int offm = __popcll(~bal & ((1ull << lane) - 1ull));
        int pos;
        if (m) { pos = basei + off; jidxg[b * 512 + pos] = j; }
        else   { pos = 511 - (basem + offm); }
        iposg[b * 512 + j] = pos;
        basei += (int)__popcll(bal);
        basem += (int)(64 - __popcll(bal));
      }
      if (lane == 0) cntg[b] = basei;
      for (int p = basei + lane; p < 512; p += 64) jidxg[b * 512 + p] = 0;
    }
  }
}

// ---------------- merged qkv GEMM + pair-bias MLP + weight transposes ------
__global__ __launch_bounds__(256) void qkv_pbias_kernel(
    const u16* __restrict__ A, const u16* __restrict__ Wt,
    u16* __restrict__ qb, u16* __restrict__ kb, u16* __restrict__ vt,
    const float* __restrict__ pf, const unsigned* __restrict__ packed,
    const u16* __restrict__ wp2t, const float* __restrict__ bp2,
    const int* __restrict__ jidxg, const int* __restrict__ cntg,
    const int* __restrict__ iposg, u16* __restrict__ biasc,
    const float* __restrict__ Wout, const float* __restrict__ Wf1,
    const float* __restrict__ Wf2, u16* __restrict__ woutt,
    u16* __restrict__ wf1t, u16* __restrict__ wf2t) {
  __shared__ uint4 smem[1024];          // 16KB shared pool
  const int blk = blockIdx.x, tid = threadIdx.x;
  const int lane = tid & 63, w = tid >> 6;
  if (blk < 384) {
    u16* As = (u16*)smem;
    u16* Bs = (u16*)smem + 64 * 64;
    const int wm = w >> 1, wn = w & 1;
    const int bm = (blk / 12) * 64, bn = (blk % 12) * 64;
    f32x4 fz = {0.f, 0.f, 0.f, 0.f};
    f32x4 acc[2][2] = {{fz, fz}, {fz, fz}};
    for (int k0 = 0; k0 < 256; k0 += 64) {
#pragma unroll
      for (int t = tid; t < 512; t += 256) {
        int r = t >> 3, s = t & 7;
        s16x8 v = *(const s16x8*)(A + (size_t)(bm + r) * 256 + k0 + s * 8);
        *(s16x8*)(As + r * 64 + ((s ^ (r & 7)) << 3)) = v;
      }
#pragma unroll
      for (int t = tid; t < 512; t += 256) {
        int r = t >> 3, s = t & 7;
        s16x8 v = *(const s16x8*)(Wt + (size_t)(bn + r) * 256 + k0 + s * 8);
        *(s16x8*)(Bs + r * 64 + ((s ^ (r & 7)) << 3)) = v;
      }
      __syncthreads();
#pragma unroll
      for (int ks = 0; ks < 2; ++ks) {
        s16x8 af[2], bf[2];
#pragma unroll
        for (int mf = 0; mf < 2; ++mf) {
          int r = wm * 32 + mf * 16 + (lane & 15);
          int s = ks * 4 + (lane >> 4);
          af[mf] = *(const s16x8*)(As + r * 64 + ((s ^ (r & 7)) << 3));
        }
#pragma unroll
        for (int nf = 0; nf < 2; ++nf) {
          int r = wn * 32 + nf * 16 + (lane & 15);
          int s = ks * 4 + (lane >> 4);
          bf[nf] = *(const s16x8*)(Bs + r * 64 + ((s ^ (r & 7)) << 3));
        }
#pragma unroll
        for (int mf = 0; mf < 2; ++mf)
#pragma unroll
          for (int nf = 0; nf < 2; ++nf)
            acc[mf][nf] = MFMA(af[mf], bf[nf], acc[mf][nf]);
      }
      __syncthreads();
    }
#pragma unroll
    for (int mf = 0; mf < 2; ++mf) {
#pragma unroll
      for (int nf = 0; nf < 2; ++nf) {
#pragma unroll
        for (int r = 0; r < 4; ++r) {
          int m = bm + wm * 32 + mf * 16 + (lane >> 4) * 4 + r;
          int n = bn + wn * 32 + nf * 16 + (lane & 15);
          float v = acc[mf][nf][r];
          if (n < 256) {
            qb[(size_t)m * 256 + n] = f2b(v * QSCALE);
          } else if (n < 512) {
            kb[(size_t)m * 256 + (n - 256)] = f2b(v);
          } else {
            int nv = n - 512, h = nv >> 5, d = nv & 31;
            int bb = m >> 9, j = m & 511;
            int pos = iposg[bb * 512 + j];
            vt[(size_t)((bb * 8 + h) * 32 + d) * 512 + pos] = f2b(v);
          }
        }
      }
    }
  } else if (blk < 2432) {
    uint4* pk = smem;                   // 128 x {w0,w1,w2,b} half2 (2KB)
    float* pfl = (float*)(smem + 128);  // 1536 floats (6KB)
    int* ji = (int*)(smem + 512);       // 512 ints (2KB)
    const int bid = blk - 384;          // b*512 + i
    const int b = bid >> 9, i = bid & 511;
    const int q = lane >> 4, hr = lane & 15;
    if (tid < 128) pk[tid] = ((const uint4*)packed)[tid];
    const float4* pfr = (const float4*)(pf + (size_t)(b * 512 + i) * 1536);
#pragma unroll
    for (int t = tid; t < 384; t += 256) ((float4*)pfl)[t] = pfr[t];
    for (int t = tid; t < 512; t += 256) ji[t] = jidxg[b * 512 + t];
    const int cnt = cntg[b];
    __syncthreads();
    __half2 f0d[8], f1d[8], f2d[8];
#pragma unroll
    for (int t = 0; t < 8; ++t) {
      int g = t * 4 + w;                // round-robin group
      if (g * 16 < cnt) {
        int jsrc = ji[g * 16 + hr];
        f0d[t] = __float2half2_rn(pfl[jsrc * 3 + 0]);
        f1d[t] = __float2half2_rn(pfl[jsrc * 3 + 1]);
        f2d[t] = __float2half2_rn(pfl[jsrc * 3 + 2]);
      }
    }
    f32x4 fz = {0.f, 0.f, 0.f, 0.f};
    f32x4 acc[8] = {fz, fz, fz, fz, fz, fz, fz, fz};
    for (int chunk = 0; chunk < 8; ++chunk) {
      f16x8 wfrag = *(const f16x8*)(wp2t + hr * 256 + chunk * 32 + q * 8);
      int pbase = chunk * 16 + q * 4;
      __half2 w0[4], w1[4], w2[4], bb[4];
#pragma unroll
      for (int p = 0; p < 4; ++p) {
        uint4 c = pk[pbase + p];
        w0[p] = *(const __half2*)&c.x;
        w1[p] = *(const __half2*)&c.y;
        w2[p] = *(const __half2*)&c.z;
        bb[p] = *(const __half2*)&c.w;
      }
#pragma unroll
      for (int t = 0; t < 8; ++t) {
        int g = t * 4 + w;
        if (g * 16 < cnt) {             // wave-uniform tile guard
          union { unsigned u[4]; f16x8 v; } af;
#pragma unroll
          for (int p = 0; p < 4; ++p) {
            __half2 h = __hfma2(f0d[t], w0[p], bb[p]);
            h = __hfma2(f1d[t], w1[p], h);
            h = __hfma2(f2d[t], w2[p], h);
            af.u[p] = pkmax0(*(const unsigned*)&h);
          }
          acc[t] = MFMAH(af.v, wfrag, acc[t]);
        }
      }
    }
    if (hr < 8) {
      float bb = bp2[hr];
      size_t base = ((size_t)(b * 8 + hr) * 512 + i) * 512;
#pragma unroll
      for (int t = 0; t < 8; ++t) {
        int g = t * 4 + w;
        if (g * 16 < cnt) {
          int p0 = g * 16 + q * 4;
          u32x2 o;
          o.x = cvtpk(acc[t][0] + bb, acc[t][1] + bb);
          o.y = cvtpk(acc[t][2] + bb, acc[t][3] + bb);
          *(u32x2*)(biasc + base + p0) = o;
        }
      }
    }
  } else if (blk < 2464) {    // Wout^T
    int o0 = (blk - 2432) * 2048;
    for (int t = tid; t < 2048; t += 256) {
      int o = o0 + t, n = o >> 8, k = o & 255;
      woutt[o] = f2b(Wout[k * 256 + n]);
    }
  } else if (blk < 2592) {    // Wf1^T
    int o0 = (blk - 2464) * 2048;
    for (int t = tid; t < 2048; t += 256) {
      int o = o0 + t, n = o >> 8, k = o & 255;
      wf1t[o] = f2b(Wf1[k * 1024 + n]);
    }
  } else {                    // Wf2^T
    int o0 = (blk - 2592) * 2048;
    for (int t = tid; t < 2048; t += 256) {
      int o = o0 + t, n = o >> 10, k = o & 1023;
      wf2t[o] = f2b(Wf2[k * 256 + n]);
    }
  }
}

// ---------------- fused flash attention: compacted keys, 8 waves -----------
__global__ __launch_bounds__(512) void flash_kernel(
    const u16* __restrict__ qb, const u16* __restrict__ kb,
    const u16* __restrict__ vt, const u16* __restrict__ biasc,
    const int* __restrict__ jidxg, const int* __restrict__ cntg,
    u16* __restrict__ aout) {
  const int i0 = blockIdx.x * 64, h = blockIdx.y, b = blockIdx.z;
  const int tid = threadIdx.x;
  const int lane = tid & 63, w = tid >> 6;
  const int mf = w & 3, jhalf = w >> 2;
  __shared__ u16 qs[64 * 32];
  __shared__ u16 ksh[128 * 32];
  __shared__ u16 vs[32 * 128];
  __shared__ u16 ps[8][16 * 64];
  __shared__ float cmb[4][2][16][2];
  __shared__ int ji[512];
  for (int t = tid; t < 512; t += 512) ji[t] = jidxg[b * 512 + t];
  for (int t = tid; t < 256; t += 512) {
    int r = t >> 2, s = t & 3;
    s16x8 v = *(const s16x8*)(qb + (size_t)(b * 512 + i0 + r) * 256 + h * 32 + s * 8);
    *(s16x8*)(qs + r * 32 + ((s ^ (r & 3)) << 3)) = v;
  }
  const int cnt = cntg[b];
  __syncthreads();
  f32x4 fz = {0.f, 0.f, 0.f, 0.f};
  f32x4 oacc[2] = {fz, fz};
  float mrun[4] = {-3e38f, -3e38f, -3e38f, -3e38f};
  float lrun[4] = {0.f, 0.f, 0.f, 0.f};
  const int jj0 = jhalf * 64;
  const int il = mf * 16 + (lane >> 4) * 4;
  const u16* bbase = biasc + ((size_t)((b * 8 + h) * 512 + i0 + il)) * 512
                   + jj0 + (lane & 15);
  const int NJT = (cnt + 127) >> 7;
  for (int jc = 0; jc < NJT; ++jc) {
    int j0 = jc * 128;
    {  // K tile (row gather via jidx)
      int r = tid >> 2, s = tid & 3;
      int jsrc = ji[j0 + r];
      s16x8 v = *(const s16x8*)(kb + (size_t)(b * 512 + jsrc) * 256 + h * 32 + s * 8);
      *(s16x8*)(ksh + r * 32 + ((s ^ (r & 3)) << 3)) = v;
    }
    {  // V tile (pos-contiguous vector load + vector swizzled store)
      int r = tid >> 4, s = tid & 15;
      s16x8 v = *(const s16x8*)(vt + (size_t)((b * 8 + h) * 32 + r) * 512 + j0 + s * 8);
      *(s16x8*)(vs + r * 128 + (((s & 8) | ((s & 7) ^ (r & 7))) << 3)) = v;
    }
    u16 bvr[4][4];
#pragma unroll
    for (int jf = 0; jf < 4; ++jf)
#pragma unroll
      for (int r = 0; r < 4; ++r)
        bvr[jf][r] = bbase[(size_t)r * 512 + j0 + jf * 16];
    __syncthreads();
    int mk[4];
#pragma unroll
    for (int jf = 0; jf < 4; ++jf)
      mk[jf] = (j0 + jj0 + jf * 16 + (lane & 15)) < cnt;
    int arow = mf * 16 + (lane & 15);
    s16x8 af = *(const s16x8*)(qs + arow * 32 + (((lane >> 4) ^ (arow & 3)) << 3));
    f32x4 sm[4];
#pragma unroll
    for (int jf = 0; jf < 4; ++jf) {
      int brow = jj0 + jf * 16 + (lane & 15);
      s16x8 bfr = *(const s16x8*)(ksh + brow * 32 + (((lane >> 4) ^ (brow & 3)) << 3));
      sm[jf] = MFMA(af, bfr, fz);
    }
#pragma unroll
    for (int jf = 0; jf < 4; ++jf) {
#pragma unroll
      for (int r = 0; r < 4; ++r) {
        float sval = sm[jf][r] + b2f(bvr[jf][r]);
        sm[jf][r] = mk[jf] ? sval : -1e9f;
      }
    }
    float mx[4];
#pragma unroll
    for (int r = 0; r < 4; ++r)
      mx[r] = fmaxf(fmaxf(sm[0][r], sm[1][r]), fmaxf(sm[2][r], sm[3][r]));
#pragma unroll
    for (int d = 1; d < 16; d <<= 1)
#pragma unroll
      for (int r = 0; r < 4; ++r) mx[r] = fmaxf(mx[r], __shfl_xor(mx[r], d));
    float psl[4] = {0.f, 0.f, 0.f, 0.f};
#pragma unroll
    for (int jf = 0; jf < 4; ++jf)
#pragma unroll
      for (int r = 0; r < 4; ++r) {
        float p = __expf(sm[jf][r] - mx[r]);
        sm[jf][r] = p; psl[r] += p;
      }
#pragma unroll
    for (int d = 1; d < 16; d <<= 1)
#pragma unroll
      for (int r = 0; r < 4; ++r) psl[r] += __shfl_xor(psl[r], d);
    if ((lane & 15) == 0) {
#pragma unroll
      for (int r = 0; r < 4; ++r) {
        int row = (lane >> 4) * 4 + r;
        cmb[mf][jhalf][row][0] = mx[r];
        cmb[mf][jhalf][row][1] = psl[r];
      }
    }
    __syncthreads();
    float selfs[4];
#pragma unroll
    for (int r = 0; r < 4; ++r) {
      int row = (lane >> 4) * 4 + r;
      float omx = cmb[mf][1 - jhalf][row][0];
      float ops = cmb[mf][1 - jhalf][row][1];
      float tm = fmaxf(mx[r], omx);
      float nm = fmaxf(mrun[r], tm);
      float sc = __expf(mrun[r] - nm);
      selfs[r] = __expf(mx[r] - nm);
      float ptile = psl[r] * selfs[r] + ops * __expf(omx - nm);
      lrun[r] = lrun[r] * sc + ptile;
      mrun[r] = nm;
      oacc[0][r] *= sc; oacc[1][r] *= sc;
    }
    u16* pw = &ps[w][0];
#pragma unroll
    for (int jf = 0; jf < 4; ++jf) {
      int jcol = jf * 16 + (lane & 15);
      int slot = jcol >> 3, el = jcol & 7;
#pragma unroll
      for (int r = 0; r < 4; ++r) {
        int row = (lane >> 4) * 4 + r;
        pw[row * 64 + ((slot ^ (row & 7)) << 3) + el] = f2b(sm[jf][r] * selfs[r]);
      }
    }
#pragma unroll
    for (int kw = 0; kw < 2; ++kw) {
      int prow = lane & 15;
      s16x8 pa = *(const s16x8*)(pw + prow * 64 + (((kw * 4 + (lane >> 4)) ^ (prow & 7)) << 3));
#pragma unroll
      for (int df = 0; df < 2; ++df) {
        int drow = df * 16 + (lane & 15);
        int jcol = jj0 + kw * 32 + ((lane >> 4) << 3);
        int slot = jcol >> 3;
        s16x8 vv = *(const s16x8*)(vs + drow * 128 + (((slot & 8) | ((slot & 7) ^ (drow & 7))) << 3));
        oacc[df] = MFMA(pa, vv, oacc[df]);
      }
    }
    __syncthreads();
  }
  float* obuf = (float*)&ps[0][0];
  if (jhalf == 1) {
#pragma unroll
    for (int r = 0; r < 4; ++r) {
      int row = mf * 16 + (lane >> 4) * 4 + r;
#pragma unroll
      for (int df = 0; df < 2; ++df)
        obuf[row * 33 + df * 16 + (lane & 15)] = oacc[df][r];
    }
  }
  __syncthreads();
  if (jhalf == 0) {
#pragma unroll
    for (int r = 0; r < 4; ++r) {
      float inv = 1.0f / lrun[r];
      int row = mf * 16 + (lane >> 4) * 4 + r;
      int i = i0 + row;
#pragma unroll
      for (int df = 0; df < 2; ++df) {
        int d = df * 16 + (lane & 15);
        float o = (oacc[df][r] + obuf[row * 33 + d]) * inv;
        aout[(size_t)(b * 512 + i) * 256 + h * 32 + d] = f2b(o);
      }
    }
  }
}

// ---------------- generic bf16 MFMA GEMM (outproj), BM=32 ------------------
__global__ __launch_bounds__(256) void mgemm_res(
    const u16* __restrict__ A, const u16* __restrict__ Wt,
    const float* __restrict__ bias, const float* __restrict__ R,
    float* __restrict__ outf, int N, int K) {
  __shared__ u16 As[32 * 64];
  __shared__ u16 Bs[64 * 64];
  const int tid = threadIdx.x;
  const int lane = tid & 63, w = tid >> 6;
  const int wm = w >> 1, wn = w & 1;
  const int bm = blockIdx.y * 32, bn = blockIdx.x * 64;
  f32x4 fz = {0.f, 0.f, 0.f, 0.f};
  f32x4 acc[2] = {fz, fz};
  for (int k0 = 0; k0 < K; k0 += 64) {
    for (int t = tid; t < 256; t += 256) {
      int r = t >> 3, s = t & 7;
      s16x8 v = *(const s16x8*)(A + (size_t)(bm + r) * K + k0 + s * 8);
      *(s16x8*)(As + r * 64 + ((s ^ (r & 7)) << 3)) = v;
    }
#pragma unroll
    for (int t = tid; t < 512; t += 256) {
      int r = t >> 3, s = t & 7;
      s16x8 v = *(const s16x8*)(Wt + (size_t)(bn + r) * K + k0 + s * 8);
      *(s16x8*)(Bs + r * 64 + ((s ^ (r & 7)) << 3)) = v;
    }
    __syncthreads();
#pragma unroll
    for (int ks = 0; ks < 2; ++ks) {
      int r = wm * 16 + (lane & 15);
      int s = ks * 4 + (lane >> 4);
      s16x8 af = *(const s16x8*)(As + r * 64 + ((s ^ (r & 7)) << 3));
#pragma unroll
      for (int nf = 0; nf < 2; ++nf) {
        int br = wn * 32 + nf * 16 + (lane & 15);
        s16x8 bf = *(const s16x8*)(Bs + br * 64 + ((s ^ (br & 7)) << 3));
        acc[nf] = MFMA(af, bf, acc[nf]);
      }
    }
    __syncthreads();
  }
#pragma unroll
  for (int nf = 0; nf < 2; ++nf) {
#pragma unroll
    for (int r = 0; r < 4; ++r) {
      int m = bm + wm * 16 + (lane >> 4) * 4 + r;
      int n = bn + wn * 32 + nf * 16 + (lane & 15);
      outf[(size_t)m * N + n] = acc[nf][r] + bias[n] + R[(size_t)m * N + n];
    }
  }
}

// ---------------- FFN1: LN1(pre1) inline -> GEMM + GELU -> h1b bf16 --------
__global__ __launch_bounds__(256) void ffn1_kernel(
    const float* __restrict__ pre1, const u16* __restrict__ Wt,
    const float* __restrict__ bias, const float* __restrict__ g1,
    const float* __restrict__ b1, u16* __restrict__ outb) {
  __shared__ u16 As[64 * 64];
  __shared__ u16 Bs[64 * 64];
  __shared__ float rowm[64], rowr[64];
  const int tid = threadIdx.x;
  const int lane = tid & 63, w = tid >> 6;
  const int wm = w >> 1, wn = w & 1;
  const int bm = blockIdx.y * 64, bn = blockIdx.x * 64;
  {
    int r = tid >> 2, qd = tid & 3;
    const float4* pr = (const float4*)(pre1 + (size_t)(bm + r) * 256 + qd * 64);
    float s = 0.f, ss = 0.f;
#pragma unroll
    for (int u = 0; u < 16; ++u) {
      float4 v = pr[u];
      s += v.x + v.y + v.z + v.w;
      ss += v.x*v.x + v.y*v.y + v.z*v.z + v.w*v.w;
    }
    s += __shfl_xor(s, 1); ss += __shfl_xor(ss, 1);
    s += __shfl_xor(s, 2); ss += __shfl_xor(ss, 2);
    if (qd == 0) {
      float mean = s * (1.0f / 256.0f);
      float var  = ss * (1.0f / 256.0f) - mean * mean;
      rowm[r] = mean; rowr[r] = rsqrtf(var + CEPS);
    }
  }
  __syncthreads();
  f32x4 fz = {0.f, 0.f, 0.f, 0.f};
  f32x4 acc[2][2] = {{fz, fz}, {fz, fz}};
  for (int k0 = 0; k0 < 256; k0 += 64) {
#pragma unroll
    for (int t = tid; t < 512; t += 256) {
      int r = t >> 3, s = t & 7;
      float mean = rowm[r], rstd = rowr[r];
      const float4* pr = (const float4*)(pre1 + (size_t)(bm + r) * 256 + k0 + s * 8);
      float4 a0 = pr[0], a1 = pr[1];
      const float4* gp = (const float4*)(g1 + k0 + s * 8);
      const float4* bp = (const float4*)(b1 + k0 + s * 8);
      float4 g0 = gp[0], g1v = gp[1], c0 = bp[0], c1 = bp[1];
      union { unsigned u[4]; s16x8 v; } pk2;
      pk2.u[0] = cvtpk((a0.x-mean)*rstd*g0.x + c0.x, (a0.y-mean)*rstd*g0.y + c0.y);
      pk2.u[1] = cvtpk((a0.z-mean)*rstd*g0.z + c0.z, (a0.w-mean)*rstd*g0.w + c0.w);
      pk2.u[2] = cvtpk((a1.x-mean)*rstd*g1v.x + c1.x, (a1.y-mean)*rstd*g1v.y + c1.y);
      pk2.u[3] = cvtpk((a1.z-mean)*rstd*g1v.z + c1.z, (a1.w-mean)*rstd*g1v.w + c1.w);
      *(s16x8*)(As + r * 64 + ((s ^ (r & 7)) << 3)) = pk2.v;
    }
#pragma unroll
    for (int t = tid; t < 512; t += 256) {
      int r = t >> 3, s = t & 7;
      s16x8 v = *(const s16x8*)(Wt + (size_t)(bn + r) * 256 + k0 + s * 8);
      *(s16x8*)(Bs + r * 64 + ((s ^ (r & 7)) << 3)) = v;
    }
    __syncthreads();
#pragma unroll
    for (int ks = 0; ks < 2; ++ks) {
      s16x8 af[2], bf[2];
#pragma unroll
      for (int mf = 0; mf < 2; ++mf) {
        int r = wm * 32 + mf * 16 + (lane & 15);
        int s = ks * 4 + (lane >> 4);
        af[mf] = *(const s16x8*)(As + r * 64 + ((s ^ (r & 7)) << 3));
      }
#pragma unroll
      for (int nf = 0; nf < 2; ++nf) {
        int r = wn * 32 + nf * 16 + (lane & 15);
        int s = ks * 4 + (lane >> 4);
        bf[nf] = *(const s16x8*)(Bs + r * 64 + ((s ^ (r & 7)) << 3));
      }
#pragma unroll
      for (int mf = 0; mf < 2; ++mf)
#pragma unroll
        for (int nf = 0; nf < 2; ++nf)
          acc[mf][nf] = MFMA(af[mf], bf[nf], acc[mf][nf]);
    }
    __syncthreads();
  }
#pragma unroll
  for (int mf = 0; mf < 2; ++mf) {
#pragma unroll
    for (int nf = 0; nf < 2; ++nf) {
#pragma unroll
      for (int r = 0; r < 4; ++r) {
        int m = bm + wm * 32 + mf * 16 + (lane >> 4) * 4 + r;
        int n = bn + wn * 32 + nf * 16 + (lane & 15);
        float gv = acc[mf][nf][r] + bias[n];
        gv = 0.5f * gv * (1.0f + erff(gv * 0.70710678118654752f));
        outb[(size_t)m * 1024 + n] = f2b(gv);
      }
    }
  }
}

// ---------------- FFN2: GEMM + bf2 + LN1-residual(pre1) inline -> pre2 -----
__global__ __launch_bounds__(256) void ffn2_kernel(
    const u16* __restrict__ A, const u16* __restrict__ Wt,
    const float* __restrict__ bias, const float* __restrict__ pre1,
    const float* __restrict__ g1, const float* __restrict__ b1,
    float* __restrict__ outf) {
  __shared__ u16 As[32 * 64];
  __shared__ u16 Bs[64 * 64];
  __shared__ float rowm[32], rowr[32];
  const int tid = threadIdx.x;
  const int lane = tid & 63, w = tid >> 6;
  const int wm = w >> 1, wn = w & 1;
  const int bm = blockIdx.y * 32, bn = blockIdx.x * 64;
  {
    int r = tid >> 3, od = tid & 7;
    const float4* pr = (const float4*)(pre1 + (size_t)(bm + r) * 256 + od * 32);
    float s = 0.f, ss = 0.f;
#pragma unroll
    for (int u = 0; u < 8; ++u) {
      float4 v = pr[u];
      s += v.x + v.y + v.z + v.w;
      ss += v.x*v.x + v.y*v.y + v.z*v.z + v.w*v.w;
    }
    s += __shfl_xor(s, 1); ss += __shfl_xor(ss, 1);
    s += __shfl_xor(s, 2); ss += __shfl_xor(ss, 2);
    s += __shfl_xor(s, 4); ss += __shfl_xor(ss, 4);
    if (od == 0) {
      float mean = s * (1.0f / 256.0f);
      float var  = ss * (1.0f / 256.0f) - mean * mean;
      rowm[r] = mean; rowr[r] = rsqrtf(var + CEPS);
    }
  }
  __syncthreads();
  f32x4 fz = {0.f, 0.f, 0.f, 0.f};
  f32x4 acc[2] = {fz, fz};
  for (int k0 = 0; k0 < 1024; k0 += 64) {
    for (int t = tid; t < 256; t += 256) {
      int r = t >> 3, s = t & 7;
      s16x8 v = *(const s16x8*)(A + (size_t)(bm + r) * 1024 + k0 + s * 8);
      *(s16x8*)(As + r * 64 + ((s ^ (r & 7)) << 3)) = v;
    }
#pragma unroll
    for (int t = tid; t < 512; t += 256) {
      int r = t >> 3, s = t & 7;
      s16x8 v = *(const s16x8*)(Wt + (size_t)(bn + r) * 1024 + k0 + s * 8);
      *(s16x8*)(Bs + r * 64 + ((s ^ (r & 7)) << 3)) = v;
    }
    __syncthreads();
#pragma unroll
    for (int ks = 0; ks < 2; ++ks) {
      int r = wm * 16 + (lane & 15);
      int s = ks * 4 + (lane >> 4);
      s16x8 af = *(const s16x8*)(As + r * 64 + ((s ^ (r & 7)) << 3));
#pragma unroll
      for (int nf = 0; nf < 2; ++nf) {
        int br = wn * 32 + nf * 16 + (lane & 15);
        s16x8 bf = *(const s16x8*)(Bs + br * 64 + ((s ^ (br & 7)) << 3));
        acc[nf] = MFMA(af, bf, acc[nf]);
      }
    }
    __syncthreads();
  }
#pragma unroll
  for (int nf = 0; nf < 2; ++nf) {
#pragma unroll
    for (int r = 0; r < 4; ++r) {
      int m = bm + wm * 16 + (lane >> 4) * 4 + r;
      int n = bn + wn * 32 + nf * 16 + (lane & 15);
      float mean = rowm[m - bm], rstd = rowr[m - bm];
      float xr = (pre1[(size_t)m * 256 + n] - mean) * rstd * g1[n] + b1[n];
      outf[(size_t)m * 256 + n] = acc[nf][r] + bias[n] + xr;
    }
  }
}

// ---------------- LayerNorm over D=256 (final) -----------------------------
__global__ __launch_bounds__(256) void ln_kernel(
    const float* __restrict__ in, const float* __restrict__ g,
    const float* __restrict__ be, float* __restrict__ op) {
  int row = blockIdx.x * 4 + (threadIdx.x >> 6);
  int lane = threadIdx.x & 63;
  const float* x = in + (size_t)row * CD;
  float4 v = *(const float4*)&x[lane * 4];
  float s  = v.x + v.y + v.z + v.w;
  float ss = v.x*v.x + v.y*v.y + v.z*v.z + v.w*v.w;
#pragma unroll
  for (int off = 32; off > 0; off >>= 1) {
    s  += __shfl_xor(s, off);
    ss += __shfl_xor(ss, off);
  }
  float mean = s * (1.0f / CD);
  float var  = ss * (1.0f / CD) - mean * mean;
  float inv  = rsqrtf(var + CEPS);
  float4 gg = *(const float4*)&g[lane * 4];
  float4 bb = *(const float4*)&be[lane * 4];
  float4 o;
  o.x = (v.x - mean) * inv * gg.x + bb.x;
  o.y = (v.y - mean) * inv * gg.y + bb.y;
  o.z = (v.z - mean) * inv * gg.z + bb.z;
  o.w = (v.w - mean) * inv * gg.w + bb.w;
  *(float4*)&op[(size_t)row * CD + lane * 4] = o;
}

extern "C" void kernel_launch(void* const* d_in, const int* in_sizes, int n_in,
                              void* d_out, int out_size, void* d_ws, size_t ws_size,
                              hipStream_t stream) {
  (void)in_sizes; (void)n_in; (void)out_size; (void)ws_size;
  const float* x    = (const float*)d_in[0];
  const void*  mask = d_in[1];
  const float* pf   = (const float*)d_in[2];
  const float* Wqkv = (const float*)d_in[3];
  const float* Wout = (const float*)d_in[4];
  const float* bout = (const float*)d_in[5];
  const float* Wp1  = (const float*)d_in[6];
  const float* bp1  = (const float*)d_in[7];
  const float* Wp2  = (const float*)d_in[8];
  const float* bp2  = (const float*)d_in[9];
  const float* Wf1  = (const float*)d_in[10];
  const float* bf1  = (const float*)d_in[11];
  const float* Wf2  = (const float*)d_in[12];
  const float* bf2  = (const float*)d_in[13];
  const float* g1   = (const float*)d_in[14];
  const float* b1   = (const float*)d_in[15];
  const float* g2   = (const float*)d_in[16];
  const float* b2   = (const float*)d_in[17];

  char* ws = (char*)d_ws;
  u16* xb     = (u16*)(ws + O_XB);
  u16* qb     = (u16*)(ws + O_QB);
  u16* kb     = (u16*)(ws + O_KB);
  u16* vt     = (u16*)(ws + O_VT);
  u16* wqkvt  = (u16*)(ws + O_WQKVT);
  u16* woutt  = (u16*)(ws + O_WOUTT);
  u16* wf1t   = (u16*)(ws + O_WF1T);
  u16* wf2t   = (u16*)(ws + O_WF2T);
  u16* wp2t   = (u16*)(ws + O_WP2T);
  unsigned* packed = (unsigned*)(ws + O_PACKED);
  int* jidxg  = (int*)(ws + O_JIDX);
  int* cntg   = (int*)(ws + O_CNT);
  int* iposg  = (int*)(ws + O_IPOS);
  u16* biasc  = (u16*)(ws + O_BIAS);
  u16* aout   = (u16*)(ws + O_AOUT);
  u16* h1b    = (u16*)(ws + O_H1B);
  float* pre1 = (float*)(ws + O_PRE1);
  float* pre2 = (float*)(ws + O_PRE2);
  float* out  = (float*)d_out;

  hipLaunchKernelGGL(prep_kernel, dim3(354), dim3(256), 0, stream,
                     x, Wqkv, Wp2, Wp1, bp1,
                     (const unsigned char*)mask,
                     xb, wqkvt, wp2t, packed, jidxg, cntg, iposg);
  // merged: qkv (384) + pbias (2048) + Wout/Wf1/Wf2 transposes (288)
  hipLaunchKernelGGL(qkv_pbias_kernel, dim3(2720), dim3(256), 0, stream,
                     xb, wqkvt, qb, kb, vt,
                     pf, packed, wp2t, bp2, jidxg, cntg, iposg, biasc,
                     Wout, Wf1, Wf2, woutt, wf1t, wf2t);
  // fused attention (compacted keys, pos-space V)
  hipLaunchKernelGGL(flash_kernel, dim3(8, 8, 4), dim3(512), 0, stream,
                     qb, kb, vt, biasc, jidxg, cntg, aout);
  // out proj + bout + residual(x) -> pre1 (f32)
  hipLaunchKernelGGL(mgemm_res, dim3(4, 64), dim3(256), 0, stream,
                     aout, woutt, bout, x, pre1, 256, 256);
  // FFN1 with inline LN1(pre1): GELU -> h1b
  hipLaunchKernelGGL(ffn1_kernel, dim3(16, 32), dim3(256), 0, stream,
                     pre1, wf1t, bf1, g1, b1, h1b);
  // FFN2 + bf2 + inline LN1-residual -> pre2
  hipLaunchKernelGGL(ffn2_kernel, dim3(4, 64), dim3(256), 0, stream,
                     h1b, wf2t, bf2, pre1, g1, b1, pre2);
  // final LN2
  hipLaunchKernelGGL(ln_kernel, dim3(M_ROWS / 4), dim3(256), 0, stream,
                     pre2, g2, b2, out);
}